// Round 1
// baseline (949.885 us; speedup 1.0000x reference)
//
#include <hip/hip_runtime.h>
#include <hip/hip_bf16.h>

#define S_LEN 2048
#define BATCH 8
#define DMODEL 512
#define NHEAD 8
#define HDIM 64

typedef unsigned short u16;
typedef __bf16 bf16_t;
typedef bf16_t bf16x8 __attribute__((ext_vector_type(8)));
typedef float f32x4 __attribute__((ext_vector_type(4)));
typedef u16 u16x8 __attribute__((ext_vector_type(8)));
typedef u16 u16x4 __attribute__((ext_vector_type(4)));

__device__ __forceinline__ u16 f2bf(float f) {
    unsigned u = __float_as_uint(f);
    u = (u + 0x7fffu + ((u >> 16) & 1u)) >> 16;
    return (u16)u;
}

__device__ __forceinline__ bf16x8 ld_frag(const u16* p) {
    u16x8 v = *(const u16x8*)p;
    return __builtin_bit_cast(bf16x8, v);
}

#define MFMA16(a, b, c) __builtin_amdgcn_mfma_f32_16x16x32_bf16((a), (b), (c), 0, 0, 0)

// ---------------- cast weights fp32 -> bf16 ----------------
__global__ __launch_bounds__(256) void cast_weights(const float* __restrict__ wq,
                                                    const float* __restrict__ wo,
                                                    u16* __restrict__ dst) {
    int i = (blockIdx.x * 256 + threadIdx.x) * 4;  // 1048576 elems total
    float4 v;
    if (i < 786432) v = *(const float4*)(wq + i);
    else            v = *(const float4*)(wo + (i - 786432));
    u16x4 o = {f2bf(v.x), f2bf(v.y), f2bf(v.z), f2bf(v.w)};
    *(u16x4*)(dst + i) = o;
}

// ---------------- QKV projection GEMM ----------------
// qkv[m][n] = sum_k src[m][k] * W[n][k] + bias[n];  m = s*8+b
// writes Qs/Ks/Vs as [b][h][s][64] bf16 (Q scaled by 1/8)
__global__ __launch_bounds__(256) void qkv_gemm(const float* __restrict__ src,
                                                const u16* __restrict__ Wq,
                                                const float* __restrict__ bias,
                                                u16* __restrict__ Qs,
                                                u16* __restrict__ Ks,
                                                u16* __restrict__ Vs) {
    __shared__ u16 Al[128][40];
    __shared__ u16 Bl[128][40];
    const int tid = threadIdx.x;
    const int lane = tid & 63, wid = tid >> 6;
    const int m0 = blockIdx.y * 128, n0 = blockIdx.x * 128;
    const int lr = lane & 15, lkg = lane >> 4, lk = lkg * 8;
    const int wr = (wid >> 1) * 64, wc = (wid & 1) * 64;
    const int ar = tid >> 1, ac = (tid & 1) * 16;

    f32x4 acc[4][4];
#pragma unroll
    for (int i = 0; i < 4; i++)
#pragma unroll
        for (int n = 0; n < 4; n++) acc[i][n] = (f32x4){0.f, 0.f, 0.f, 0.f};

    for (int k0 = 0; k0 < DMODEL; k0 += 32) {
        __syncthreads();
        {
            const float* sp = src + (size_t)(m0 + ar) * DMODEL + k0 + ac;
            float4 v0 = *(const float4*)(sp + 0);
            float4 v1 = *(const float4*)(sp + 4);
            float4 v2 = *(const float4*)(sp + 8);
            float4 v3 = *(const float4*)(sp + 12);
            u16x8 p0 = {f2bf(v0.x), f2bf(v0.y), f2bf(v0.z), f2bf(v0.w),
                        f2bf(v1.x), f2bf(v1.y), f2bf(v1.z), f2bf(v1.w)};
            u16x8 p1 = {f2bf(v2.x), f2bf(v2.y), f2bf(v2.z), f2bf(v2.w),
                        f2bf(v3.x), f2bf(v3.y), f2bf(v3.z), f2bf(v3.w)};
            *(u16x8*)&Al[ar][ac] = p0;
            *(u16x8*)&Al[ar][ac + 8] = p1;
            const u16* wp = Wq + (size_t)(n0 + ar) * DMODEL + k0 + ac;
            *(u16x8*)&Bl[ar][ac] = *(const u16x8*)wp;
            *(u16x8*)&Bl[ar][ac + 8] = *(const u16x8*)(wp + 8);
        }
        __syncthreads();
        bf16x8 af[4], bfr[4];
#pragma unroll
        for (int i = 0; i < 4; i++) af[i] = ld_frag(&Al[wr + i * 16 + lr][lk]);
#pragma unroll
        for (int n = 0; n < 4; n++) bfr[n] = ld_frag(&Bl[wc + n * 16 + lr][lk]);
#pragma unroll
        for (int i = 0; i < 4; i++)
#pragma unroll
            for (int n = 0; n < 4; n++) acc[i][n] = MFMA16(af[i], bfr[n], acc[i][n]);
    }

    float bv[4];
#pragma unroll
    for (int n = 0; n < 4; n++) bv[n] = bias[n0 + wc + n * 16 + lr];
#pragma unroll
    for (int i = 0; i < 4; i++) {
#pragma unroll
        for (int n = 0; n < 4; n++) {
            int ncol = n0 + wc + n * 16 + lr;
            int sect = ncol >> 9, idx = ncol & 511;
            int h = idx >> 6, d = idx & 63;
#pragma unroll
            for (int j = 0; j < 4; j++) {
                int m = m0 + wr + i * 16 + lkg * 4 + j;
                int srow = m >> 3, bidx = m & 7;
                float val = acc[i][n][j] + bv[n];
                size_t o = (((size_t)(bidx * NHEAD + h) * S_LEN) + srow) * HDIM + d;
                if (sect == 0)      Qs[o] = f2bf(val * 0.125f);
                else if (sect == 1) Ks[o] = f2bf(val);
                else                Vs[o] = f2bf(val);
            }
        }
    }
}

// ---------------- transpose V: [bh][s][64] -> [bh][64][s] ----------------
__global__ __launch_bounds__(256) void transpose_v(const u16* __restrict__ Vs,
                                                   u16* __restrict__ Vt) {
    __shared__ u16 tile[64][70];
    int bh = blockIdx.y, t0 = blockIdx.x * 64;
    int tid = threadIdx.x;
    int r = tid >> 2, c = (tid & 3) * 16;
    const u16* vp = Vs + ((size_t)bh * S_LEN + t0 + r) * HDIM + c;
    u16x8 x0 = *(const u16x8*)vp;
    u16x8 x1 = *(const u16x8*)(vp + 8);
#pragma unroll
    for (int i = 0; i < 8; i++) tile[r][c + i] = x0[i];
#pragma unroll
    for (int i = 0; i < 8; i++) tile[r][c + 8 + i] = x1[i];
    __syncthreads();
    int d0 = tid >> 2, tt = (tid & 3) * 16;
    u16x8 y0, y1;
#pragma unroll
    for (int i = 0; i < 8; i++) y0[i] = tile[tt + i][d0];
#pragma unroll
    for (int i = 0; i < 8; i++) y1[i] = tile[tt + 8 + i][d0];
    u16* op = Vt + ((size_t)bh * HDIM + d0) * S_LEN + t0 + tt;
    *(u16x8*)op = y0;
    *(u16x8*)(op + 8) = y1;
}

// ---------------- LSE (online row max / sumexp) ----------------
__global__ __launch_bounds__(256) void lse_kernel(const u16* __restrict__ Qs,
                                                  const u16* __restrict__ Ks,
                                                  float* __restrict__ Lm,
                                                  float* __restrict__ Ll) {
    __shared__ u16 Kl[64][72];
    int bh = blockIdx.y, s0 = blockIdx.x * 64;
    int tid = threadIdx.x, lane = tid & 63, wid = tid >> 6;
    int lr = lane & 15, lkg = lane >> 4, lk = lkg * 8;
    const u16* Qb = Qs + (size_t)bh * S_LEN * HDIM;
    const u16* Kb = Ks + (size_t)bh * S_LEN * HDIM;
    int qrow = s0 + wid * 16 + lr;
    bf16x8 a0 = ld_frag(Qb + (size_t)qrow * HDIM + lk);
    bf16x8 a1 = ld_frag(Qb + (size_t)qrow * HDIM + 32 + lk);
    float mrow[4] = {-1e30f, -1e30f, -1e30f, -1e30f};
    float lsum[4] = {0.f, 0.f, 0.f, 0.f};
    int kr = tid >> 2, kc = (tid & 3) * 16;

    for (int t0 = 0; t0 < S_LEN; t0 += 64) {
        __syncthreads();
        {
            const u16* kp = Kb + (size_t)(t0 + kr) * HDIM + kc;
            *(u16x8*)&Kl[kr][kc] = *(const u16x8*)kp;
            *(u16x8*)&Kl[kr][kc + 8] = *(const u16x8*)(kp + 8);
        }
        __syncthreads();
        f32x4 sc[4];
#pragma unroll
        for (int n = 0; n < 4; n++) sc[n] = (f32x4){0.f, 0.f, 0.f, 0.f};
#pragma unroll
        for (int n = 0; n < 4; n++) {
            bf16x8 b0 = ld_frag(&Kl[n * 16 + lr][lk]);
            bf16x8 b1 = ld_frag(&Kl[n * 16 + lr][32 + lk]);
            sc[n] = MFMA16(a0, b0, sc[n]);
            sc[n] = MFMA16(a1, b1, sc[n]);
        }
#pragma unroll
        for (int j = 0; j < 4; j++) {
            float tmax = fmaxf(fmaxf(sc[0][j], sc[1][j]), fmaxf(sc[2][j], sc[3][j]));
#pragma unroll
            for (int off = 1; off < 16; off <<= 1) tmax = fmaxf(tmax, __shfl_xor(tmax, off));
            float nm = fmaxf(mrow[j], tmax);
            float ss = 0.f;
#pragma unroll
            for (int n = 0; n < 4; n++) ss += __expf(sc[n][j] - nm);
#pragma unroll
            for (int off = 1; off < 16; off <<= 1) ss += __shfl_xor(ss, off);
            lsum[j] = lsum[j] * __expf(mrow[j] - nm) + ss;
            mrow[j] = nm;
        }
    }
    if (lr == 0) {
#pragma unroll
        for (int j = 0; j < 4; j++) {
            int row = s0 + wid * 16 + lkg * 4 + j;
            Lm[(size_t)bh * S_LEN + row] = mrow[j];
            Ll[(size_t)bh * S_LEN + row] = lsum[j];
        }
    }
}

// ---------------- mean of attention over heads ----------------
// grid (S/16, B); waves split the t dimension; h loop inner, accumulate P/8.
__global__ __launch_bounds__(256) void mean_kernel(const u16* __restrict__ Qs,
                                                   const u16* __restrict__ Ks,
                                                   const float* __restrict__ Lm,
                                                   const float* __restrict__ Ll,
                                                   float* __restrict__ attnw) {
    int b = blockIdx.y, r0 = blockIdx.x * 16;
    int tid = threadIdx.x, lane = tid & 63, wid = tid >> 6;
    int lr = lane & 15, lkg = lane >> 4, lk = lkg * 8;

    for (int it = 0; it < 8; ++it) {
        int t0 = it * 256 + wid * 64;
        f32x4 macc[4];
#pragma unroll
        for (int n = 0; n < 4; n++) macc[n] = (f32x4){0.f, 0.f, 0.f, 0.f};
        for (int h = 0; h < 8; ++h) {
            int bh = b * 8 + h;
            const u16* Qb = Qs + (size_t)bh * S_LEN * HDIM;
            const u16* Kb = Ks + (size_t)bh * S_LEN * HDIM;
            bf16x8 a0 = ld_frag(Qb + (size_t)(r0 + lr) * HDIM + lk);
            bf16x8 a1 = ld_frag(Qb + (size_t)(r0 + lr) * HDIM + 32 + lk);
            f32x4 sc[4];
#pragma unroll
            for (int n = 0; n < 4; n++) sc[n] = (f32x4){0.f, 0.f, 0.f, 0.f};
#pragma unroll
            for (int n = 0; n < 4; n++) {
                const u16* kp = Kb + (size_t)(t0 + n * 16 + lr) * HDIM;
                bf16x8 b0 = ld_frag(kp + lk);
                bf16x8 b1 = ld_frag(kp + 32 + lk);
                sc[n] = MFMA16(a0, b0, sc[n]);
                sc[n] = MFMA16(a1, b1, sc[n]);
            }
            float mj[4], cj[4];
#pragma unroll
            for (int j = 0; j < 4; j++) {
                int row = r0 + lkg * 4 + j;
                mj[j] = Lm[(size_t)bh * S_LEN + row];
                cj[j] = 0.125f / Ll[(size_t)bh * S_LEN + row];
            }
#pragma unroll
            for (int n = 0; n < 4; n++)
#pragma unroll
                for (int j = 0; j < 4; j++)
                    macc[n][j] += __expf(sc[n][j] - mj[j]) * cj[j];
        }
#pragma unroll
        for (int n = 0; n < 4; n++)
#pragma unroll
            for (int j = 0; j < 4; j++) {
                int row = r0 + lkg * 4 + j;
                int t = t0 + n * 16 + lr;
                attnw[((size_t)b * S_LEN + row) * S_LEN + t] = macc[n][j];
            }
    }
}

// ---------------- context: P @ V ----------------
__global__ __launch_bounds__(256) void ctx_kernel(const u16* __restrict__ Qs,
                                                  const u16* __restrict__ Ks,
                                                  const u16* __restrict__ Vt,
                                                  const float* __restrict__ Lm,
                                                  const float* __restrict__ Ll,
                                                  u16* __restrict__ Ctx) {
    __shared__ u16 Kl[64][72];
    __shared__ u16 Pl[4][16][72];
    int bh = blockIdx.y, b = bh >> 3, h = bh & 7;
    int s0 = blockIdx.x * 64;
    int tid = threadIdx.x, lane = tid & 63, wid = tid >> 6;
    int lr = lane & 15, lkg = lane >> 4, lk = lkg * 8;
    const u16* Qb = Qs + (size_t)bh * S_LEN * HDIM;
    const u16* Kb = Ks + (size_t)bh * S_LEN * HDIM;
    const u16* Vb = Vt + (size_t)bh * HDIM * S_LEN;
    int qrow = s0 + wid * 16 + lr;
    bf16x8 a0 = ld_frag(Qb + (size_t)qrow * HDIM + lk);
    bf16x8 a1 = ld_frag(Qb + (size_t)qrow * HDIM + 32 + lk);
    float mj[4], cj[4];
#pragma unroll
    for (int j = 0; j < 4; j++) {
        int row = s0 + wid * 16 + lkg * 4 + j;
        mj[j] = Lm[(size_t)bh * S_LEN + row];
        cj[j] = 1.f / Ll[(size_t)bh * S_LEN + row];
    }
    f32x4 cacc[4];
#pragma unroll
    for (int n = 0; n < 4; n++) cacc[n] = (f32x4){0.f, 0.f, 0.f, 0.f};
    int kr = tid >> 2, kc = (tid & 3) * 16;

    for (int t0 = 0; t0 < S_LEN; t0 += 64) {
        __syncthreads();
        {
            const u16* kp = Kb + (size_t)(t0 + kr) * HDIM + kc;
            *(u16x8*)&Kl[kr][kc] = *(const u16x8*)kp;
            *(u16x8*)&Kl[kr][kc + 8] = *(const u16x8*)(kp + 8);
        }
        __syncthreads();
        f32x4 sc[4];
#pragma unroll
        for (int n = 0; n < 4; n++) sc[n] = (f32x4){0.f, 0.f, 0.f, 0.f};
#pragma unroll
        for (int n = 0; n < 4; n++) {
            bf16x8 b0 = ld_frag(&Kl[n * 16 + lr][lk]);
            bf16x8 b1 = ld_frag(&Kl[n * 16 + lr][32 + lk]);
            sc[n] = MFMA16(a0, b0, sc[n]);
            sc[n] = MFMA16(a1, b1, sc[n]);
        }
#pragma unroll
        for (int n = 0; n < 4; n++)
#pragma unroll
            for (int j = 0; j < 4; j++) {
                float p = __expf(sc[n][j] - mj[j]) * cj[j];
                Pl[wid][lkg * 4 + j][n * 16 + lr] = f2bf(p);
            }
        bf16x8 p0 = ld_frag(&Pl[wid][lr][lk]);
        bf16x8 p1 = ld_frag(&Pl[wid][lr][32 + lk]);
#pragma unroll
        for (int n = 0; n < 4; n++) {
            const u16* vp = Vb + (size_t)(n * 16 + lr) * S_LEN + t0;
            bf16x8 v0 = ld_frag(vp + lk);
            bf16x8 v1 = ld_frag(vp + 32 + lk);
            cacc[n] = MFMA16(p0, v0, cacc[n]);
            cacc[n] = MFMA16(p1, v1, cacc[n]);
        }
    }
#pragma unroll
    for (int n = 0; n < 4; n++)
#pragma unroll
        for (int j = 0; j < 4; j++) {
            int srow = s0 + wid * 16 + lkg * 4 + j;
            int d = n * 16 + lr;
            Ctx[((size_t)srow * BATCH + b) * DMODEL + h * 64 + d] = f2bf(cacc[n][j]);
        }
}

// ---------------- output projection GEMM ----------------
__global__ __launch_bounds__(256) void out_gemm(const u16* __restrict__ Ctx,
                                                const u16* __restrict__ Wo,
                                                const float* __restrict__ obias,
                                                float* __restrict__ out) {
    __shared__ u16 Al[128][40];
    __shared__ u16 Bl[128][40];
    const int tid = threadIdx.x;
    const int lane = tid & 63, wid = tid >> 6;
    const int m0 = blockIdx.y * 128, n0 = blockIdx.x * 128;
    const int lr = lane & 15, lkg = lane >> 4, lk = lkg * 8;
    const int wr = (wid >> 1) * 64, wc = (wid & 1) * 64;
    const int ar = tid >> 1, ac = (tid & 1) * 16;

    f32x4 acc[4][4];
#pragma unroll
    for (int i = 0; i < 4; i++)
#pragma unroll
        for (int n = 0; n < 4; n++) acc[i][n] = (f32x4){0.f, 0.f, 0.f, 0.f};

    for (int k0 = 0; k0 < DMODEL; k0 += 32) {
        __syncthreads();
        {
            const u16* apz = Ctx + (size_t)(m0 + ar) * DMODEL + k0 + ac;
            *(u16x8*)&Al[ar][ac] = *(const u16x8*)apz;
            *(u16x8*)&Al[ar][ac + 8] = *(const u16x8*)(apz + 8);
            const u16* wp = Wo + (size_t)(n0 + ar) * DMODEL + k0 + ac;
            *(u16x8*)&Bl[ar][ac] = *(const u16x8*)wp;
            *(u16x8*)&Bl[ar][ac + 8] = *(const u16x8*)(wp + 8);
        }
        __syncthreads();
        bf16x8 af[4], bfr[4];
#pragma unroll
        for (int i = 0; i < 4; i++) af[i] = ld_frag(&Al[wr + i * 16 + lr][lk]);
#pragma unroll
        for (int n = 0; n < 4; n++) bfr[n] = ld_frag(&Bl[wc + n * 16 + lr][lk]);
#pragma unroll
        for (int i = 0; i < 4; i++)
#pragma unroll
            for (int n = 0; n < 4; n++) acc[i][n] = MFMA16(af[i], bfr[n], acc[i][n]);
    }

    float bv[4];
#pragma unroll
    for (int n = 0; n < 4; n++) bv[n] = obias[n0 + wc + n * 16 + lr];
#pragma unroll
    for (int i = 0; i < 4; i++)
#pragma unroll
        for (int n = 0; n < 4; n++) {
            int ncol = n0 + wc + n * 16 + lr;
#pragma unroll
            for (int j = 0; j < 4; j++) {
                int m = m0 + wr + i * 16 + lkg * 4 + j;
                out[(size_t)m * DMODEL + ncol] = acc[i][n][j] + bv[n];
            }
        }
}

extern "C" void kernel_launch(void* const* d_in, const int* in_sizes, int n_in,
                              void* d_out, int out_size, void* d_ws, size_t ws_size,
                              hipStream_t stream) {
    const float* src   = (const float*)d_in[0];
    const float* w_in  = (const float*)d_in[1];
    const float* b_in  = (const float*)d_in[2];
    const float* w_out = (const float*)d_in[3];
    const float* b_out = (const float*)d_in[4];
    float* out = (float*)d_out;
    float* attnw = out + (size_t)S_LEN * BATCH * DMODEL;  // [B,S,S]

    // workspace layout
    float* Lm = (float*)d_ws;            // 131072
    float* Ll = Lm + 131072;             // 131072
    u16* Wqb = (u16*)(Ll + 131072);      // 786432
    u16* Wob = Wqb + 786432;             // 262144
    u16* Qs  = Wob + 262144;             // 8388608 each
    u16* Ks  = Qs + 8388608;
    u16* Vs  = Ks + 8388608;
    u16* Vt  = Vs + 8388608;
    u16* Ctx = Vt + 8388608;

    cast_weights<<<dim3(1024), dim3(256), 0, stream>>>(w_in, w_out, Wqb);
    qkv_gemm<<<dim3(12, 128), dim3(256), 0, stream>>>(src, Wqb, b_in, Qs, Ks, Vs);
    transpose_v<<<dim3(32, 64), dim3(256), 0, stream>>>(Vs, Vt);
    lse_kernel<<<dim3(32, 64), dim3(256), 0, stream>>>(Qs, Ks, Lm, Ll);
    mean_kernel<<<dim3(128, 8), dim3(256), 0, stream>>>(Qs, Ks, Lm, Ll, attnw);
    ctx_kernel<<<dim3(32, 64), dim3(256), 0, stream>>>(Qs, Ks, Vt, Lm, Ll, Ctx);
    out_gemm<<<dim3(4, 128), dim3(256), 0, stream>>>(Ctx, Wob, b_out, out);
}

// Round 2
// 617.779 us; speedup vs baseline: 1.5376x; 1.5376x over previous
//
#include <hip/hip_runtime.h>
#include <hip/hip_bf16.h>

#define S_LEN 2048
#define BATCH 8
#define DMODEL 512
#define NHEAD 8
#define HDIM 64

// Q pre-scale: (1/8) * log2(e) so softmax exponentials are raw v_exp_f32 (exp2)
#define QSCALE 0.18033688011112042f

typedef unsigned short u16;
typedef __bf16 bf16_t;
typedef bf16_t bf16x8 __attribute__((ext_vector_type(8)));
typedef float f32x4 __attribute__((ext_vector_type(4)));
typedef u16 u16x8 __attribute__((ext_vector_type(8)));
typedef u16 u16x4 __attribute__((ext_vector_type(4)));

__device__ __forceinline__ u16 f2bf(float f) {
    unsigned u = __float_as_uint(f);
    u = (u + 0x7fffu + ((u >> 16) & 1u)) >> 16;
    return (u16)u;
}

__device__ __forceinline__ bf16x8 ld_frag(const u16* p) {
    u16x8 v = *(const u16x8*)p;
    return __builtin_bit_cast(bf16x8, v);
}

#define MFMA16(a, b, c) __builtin_amdgcn_mfma_f32_16x16x32_bf16((a), (b), (c), 0, 0, 0)
#define EXP2F(x) __builtin_amdgcn_exp2f(x)

// ---------------- cast weights fp32 -> bf16 ----------------
__global__ __launch_bounds__(256) void cast_weights(const float* __restrict__ wq,
                                                    const float* __restrict__ wo,
                                                    u16* __restrict__ dst) {
    int i = (blockIdx.x * 256 + threadIdx.x) * 4;  // 1048576 elems total
    float4 v;
    if (i < 786432) v = *(const float4*)(wq + i);
    else            v = *(const float4*)(wo + (i - 786432));
    u16x4 o = {f2bf(v.x), f2bf(v.y), f2bf(v.z), f2bf(v.w)};
    *(u16x4*)(dst + i) = o;
}

// ---------------- QKV projection GEMM ----------------
// qkv[m][n] = sum_k src[m][k] * W[n][k] + bias[n];  m = s*8+b
// writes Qs/Ks/Vs as [b][h][s][64] bf16 (Q scaled by QSCALE)
__global__ __launch_bounds__(256) void qkv_gemm(const float* __restrict__ src,
                                                const u16* __restrict__ Wq,
                                                const float* __restrict__ bias,
                                                u16* __restrict__ Qs,
                                                u16* __restrict__ Ks,
                                                u16* __restrict__ Vs) {
    __shared__ u16 Al[128][40];
    __shared__ u16 Bl[128][40];
    const int tid = threadIdx.x;
    const int lane = tid & 63, wid = tid >> 6;
    const int m0 = blockIdx.y * 128, n0 = blockIdx.x * 128;
    const int lr = lane & 15, lkg = lane >> 4, lk = lkg * 8;
    const int wr = (wid >> 1) * 64, wc = (wid & 1) * 64;
    const int ar = tid >> 1, ac = (tid & 1) * 16;

    f32x4 acc[4][4];
#pragma unroll
    for (int i = 0; i < 4; i++)
#pragma unroll
        for (int n = 0; n < 4; n++) acc[i][n] = (f32x4){0.f, 0.f, 0.f, 0.f};

    for (int k0 = 0; k0 < DMODEL; k0 += 32) {
        __syncthreads();
        {
            const float* sp = src + (size_t)(m0 + ar) * DMODEL + k0 + ac;
            float4 v0 = *(const float4*)(sp + 0);
            float4 v1 = *(const float4*)(sp + 4);
            float4 v2 = *(const float4*)(sp + 8);
            float4 v3 = *(const float4*)(sp + 12);
            u16x8 p0 = {f2bf(v0.x), f2bf(v0.y), f2bf(v0.z), f2bf(v0.w),
                        f2bf(v1.x), f2bf(v1.y), f2bf(v1.z), f2bf(v1.w)};
            u16x8 p1 = {f2bf(v2.x), f2bf(v2.y), f2bf(v2.z), f2bf(v2.w),
                        f2bf(v3.x), f2bf(v3.y), f2bf(v3.z), f2bf(v3.w)};
            *(u16x8*)&Al[ar][ac] = p0;
            *(u16x8*)&Al[ar][ac + 8] = p1;
            const u16* wp = Wq + (size_t)(n0 + ar) * DMODEL + k0 + ac;
            *(u16x8*)&Bl[ar][ac] = *(const u16x8*)wp;
            *(u16x8*)&Bl[ar][ac + 8] = *(const u16x8*)(wp + 8);
        }
        __syncthreads();
        bf16x8 af[4], bfr[4];
#pragma unroll
        for (int i = 0; i < 4; i++) af[i] = ld_frag(&Al[wr + i * 16 + lr][lk]);
#pragma unroll
        for (int n = 0; n < 4; n++) bfr[n] = ld_frag(&Bl[wc + n * 16 + lr][lk]);
#pragma unroll
        for (int i = 0; i < 4; i++)
#pragma unroll
            for (int n = 0; n < 4; n++) acc[i][n] = MFMA16(af[i], bfr[n], acc[i][n]);
    }

    float bv[4];
#pragma unroll
    for (int n = 0; n < 4; n++) bv[n] = bias[n0 + wc + n * 16 + lr];
#pragma unroll
    for (int i = 0; i < 4; i++) {
#pragma unroll
        for (int n = 0; n < 4; n++) {
            int ncol = n0 + wc + n * 16 + lr;
            int sect = ncol >> 9, idx = ncol & 511;
            int h = idx >> 6, d = idx & 63;
#pragma unroll
            for (int j = 0; j < 4; j++) {
                int m = m0 + wr + i * 16 + lkg * 4 + j;
                int srow = m >> 3, bidx = m & 7;
                float val = acc[i][n][j] + bv[n];
                size_t o = (((size_t)(bidx * NHEAD + h) * S_LEN) + srow) * HDIM + d;
                if (sect == 0)      Qs[o] = f2bf(val * QSCALE);
                else if (sect == 1) Ks[o] = f2bf(val);
                else                Vs[o] = f2bf(val);
            }
        }
    }
}

// ---------------- transpose V: [bh][s][64] -> [bh][64][s] ----------------
__global__ __launch_bounds__(256) void transpose_v(const u16* __restrict__ Vs,
                                                   u16* __restrict__ Vt) {
    __shared__ u16 tile[64][70];
    int bh = blockIdx.y, t0 = blockIdx.x * 64;
    int tid = threadIdx.x;
    int r = tid >> 2, c = (tid & 3) * 16;
    const u16* vp = Vs + ((size_t)bh * S_LEN + t0 + r) * HDIM + c;
    u16x8 x0 = *(const u16x8*)vp;
    u16x8 x1 = *(const u16x8*)(vp + 8);
#pragma unroll
    for (int i = 0; i < 8; i++) tile[r][c + i] = x0[i];
#pragma unroll
    for (int i = 0; i < 8; i++) tile[r][c + 8 + i] = x1[i];
    __syncthreads();
    int d0 = tid >> 2, tt = (tid & 3) * 16;
    u16x8 y0, y1;
#pragma unroll
    for (int i = 0; i < 8; i++) y0[i] = tile[tt + i][d0];
#pragma unroll
    for (int i = 0; i < 8; i++) y1[i] = tile[tt + 8 + i][d0];
    u16* op = Vt + ((size_t)bh * HDIM + d0) * S_LEN + t0 + tt;
    *(u16x8*)op = y0;
    *(u16x8*)(op + 8) = y1;
}

// ---------------- context: flash-style (no precomputed LSE) ----------------
// Computes ctx = softmax(QK^T) V for one (bh, 64 q-rows) and writes the
// per-row reciprocal softmax denominator (1/l) for mean_kernel to reuse.
__global__ __launch_bounds__(256) void ctx_kernel(const u16* __restrict__ Qs,
                                                  const u16* __restrict__ Ks,
                                                  const u16* __restrict__ Vt,
                                                  float* __restrict__ Lr,
                                                  u16* __restrict__ Ctx) {
    __shared__ u16 Kl[64][72];
    __shared__ u16 Pl[4][16][72];
    int bh = blockIdx.y, b = bh >> 3, h = bh & 7;
    int s0 = blockIdx.x * 64;
    int tid = threadIdx.x, lane = tid & 63, wid = tid >> 6;
    int lr = lane & 15, lkg = lane >> 4, lk = lkg * 8;
    const u16* Qb = Qs + (size_t)bh * S_LEN * HDIM;
    const u16* Kb = Ks + (size_t)bh * S_LEN * HDIM;
    const u16* Vb = Vt + (size_t)bh * HDIM * S_LEN;
    int qrow = s0 + wid * 16 + lr;
    bf16x8 a0 = ld_frag(Qb + (size_t)qrow * HDIM + lk);
    bf16x8 a1 = ld_frag(Qb + (size_t)qrow * HDIM + 32 + lk);
    float lsum[4] = {0.f, 0.f, 0.f, 0.f};
    f32x4 cacc[4];
#pragma unroll
    for (int n = 0; n < 4; n++) cacc[n] = (f32x4){0.f, 0.f, 0.f, 0.f};
    int kr = tid >> 2, kc = (tid & 3) * 16;

    for (int t0 = 0; t0 < S_LEN; t0 += 64) {
        __syncthreads();
        {
            const u16* kp = Kb + (size_t)(t0 + kr) * HDIM + kc;
            *(u16x8*)&Kl[kr][kc] = *(const u16x8*)kp;
            *(u16x8*)&Kl[kr][kc + 8] = *(const u16x8*)(kp + 8);
        }
        __syncthreads();
        f32x4 sc[4];
#pragma unroll
        for (int n = 0; n < 4; n++) sc[n] = (f32x4){0.f, 0.f, 0.f, 0.f};
#pragma unroll
        for (int n = 0; n < 4; n++) {
            bf16x8 b0 = ld_frag(&Kl[n * 16 + lr][lk]);
            bf16x8 b1 = ld_frag(&Kl[n * 16 + lr][32 + lk]);
            sc[n] = MFMA16(a0, b0, sc[n]);
            sc[n] = MFMA16(a1, b1, sc[n]);
        }
        // unnormalized exp2; accumulate row sums; stash P (bf16) for PV
#pragma unroll
        for (int n = 0; n < 4; n++)
#pragma unroll
            for (int j = 0; j < 4; j++) {
                float e = EXP2F(sc[n][j]);
                lsum[j] += e;
                Pl[wid][lkg * 4 + j][n * 16 + lr] = f2bf(e);
            }
        bf16x8 p0 = ld_frag(&Pl[wid][lr][lk]);
        bf16x8 p1 = ld_frag(&Pl[wid][lr][32 + lk]);
#pragma unroll
        for (int n = 0; n < 4; n++) {
            const u16* vp = Vb + (size_t)(n * 16 + lr) * S_LEN + t0;
            bf16x8 v0 = ld_frag(vp + lk);
            bf16x8 v1 = ld_frag(vp + 32 + lk);
            cacc[n] = MFMA16(p0, v0, cacc[n]);
            cacc[n] = MFMA16(p1, v1, cacc[n]);
        }
    }

    // finish row sums across the 16 col-residue lanes
    float cj[4];
#pragma unroll
    for (int j = 0; j < 4; j++) {
        float s = lsum[j];
#pragma unroll
        for (int off = 1; off < 16; off <<= 1) s += __shfl_xor(s, off);
        cj[j] = 1.f / s;
    }
    if (lr == 0) {
#pragma unroll
        for (int j = 0; j < 4; j++)
            Lr[(size_t)bh * S_LEN + s0 + wid * 16 + lkg * 4 + j] = cj[j];
    }
#pragma unroll
    for (int n = 0; n < 4; n++)
#pragma unroll
        for (int j = 0; j < 4; j++) {
            int srow = s0 + wid * 16 + lkg * 4 + j;
            int d = n * 16 + lr;
            Ctx[((size_t)srow * BATCH + b) * DMODEL + h * 64 + d] = f2bf(cacc[n][j] * cj[j]);
        }
}

// ---------------- mean of attention over heads ----------------
// One block = 64x64 (s x t) tile of attnw for one batch; sums over 8 heads.
__global__ __launch_bounds__(256) void mean_kernel(const u16* __restrict__ Qs,
                                                   const u16* __restrict__ Ks,
                                                   const float* __restrict__ Lr,
                                                   float* __restrict__ attnw) {
    __shared__ u16 Kl[64][72];
    int b = blockIdx.y;
    int r0 = (blockIdx.x & 31) * 64, t0 = (blockIdx.x >> 5) * 64;
    int tid = threadIdx.x, lane = tid & 63, wid = tid >> 6;
    int lr = lane & 15, lkg = lane >> 4, lk = lkg * 8;
    int kr = tid >> 2, kc = (tid & 3) * 16;

    // preload 1/(8*l) for all heads (rows fixed per thread)
    float cjh[8][4];
#pragma unroll
    for (int h = 0; h < 8; h++)
#pragma unroll
        for (int j = 0; j < 4; j++)
            cjh[h][j] = 0.125f *
                Lr[(size_t)(b * 8 + h) * S_LEN + r0 + wid * 16 + lkg * 4 + j];

    f32x4 macc[4];
#pragma unroll
    for (int n = 0; n < 4; n++) macc[n] = (f32x4){0.f, 0.f, 0.f, 0.f};

#pragma unroll
    for (int h = 0; h < 8; h++) {
        int bh = b * 8 + h;
        const u16* Qb = Qs + (size_t)bh * S_LEN * HDIM;
        const u16* Kb = Ks + (size_t)bh * S_LEN * HDIM;
        __syncthreads();
        {
            const u16* kp = Kb + (size_t)(t0 + kr) * HDIM + kc;
            *(u16x8*)&Kl[kr][kc] = *(const u16x8*)kp;
            *(u16x8*)&Kl[kr][kc + 8] = *(const u16x8*)(kp + 8);
        }
        __syncthreads();
        bf16x8 a0 = ld_frag(Qb + (size_t)(r0 + wid * 16 + lr) * HDIM + lk);
        bf16x8 a1 = ld_frag(Qb + (size_t)(r0 + wid * 16 + lr) * HDIM + 32 + lk);
        f32x4 sc[4];
#pragma unroll
        for (int n = 0; n < 4; n++) sc[n] = (f32x4){0.f, 0.f, 0.f, 0.f};
#pragma unroll
        for (int n = 0; n < 4; n++) {
            bf16x8 b0 = ld_frag(&Kl[n * 16 + lr][lk]);
            bf16x8 b1 = ld_frag(&Kl[n * 16 + lr][32 + lk]);
            sc[n] = MFMA16(a0, b0, sc[n]);
            sc[n] = MFMA16(a1, b1, sc[n]);
        }
#pragma unroll
        for (int n = 0; n < 4; n++)
#pragma unroll
            for (int j = 0; j < 4; j++)
                macc[n][j] += EXP2F(sc[n][j]) * cjh[h][j];
    }

#pragma unroll
    for (int n = 0; n < 4; n++)
#pragma unroll
        for (int j = 0; j < 4; j++) {
            int row = r0 + wid * 16 + lkg * 4 + j;
            attnw[((size_t)b * S_LEN + row) * S_LEN + t0 + n * 16 + lr] = macc[n][j];
        }
}

// ---------------- output projection GEMM ----------------
__global__ __launch_bounds__(256) void out_gemm(const u16* __restrict__ Ctx,
                                                const u16* __restrict__ Wo,
                                                const float* __restrict__ obias,
                                                float* __restrict__ out) {
    __shared__ u16 Al[128][40];
    __shared__ u16 Bl[128][40];
    const int tid = threadIdx.x;
    const int lane = tid & 63, wid = tid >> 6;
    const int m0 = blockIdx.y * 128, n0 = blockIdx.x * 128;
    const int lr = lane & 15, lkg = lane >> 4, lk = lkg * 8;
    const int wr = (wid >> 1) * 64, wc = (wid & 1) * 64;
    const int ar = tid >> 1, ac = (tid & 1) * 16;

    f32x4 acc[4][4];
#pragma unroll
    for (int i = 0; i < 4; i++)
#pragma unroll
        for (int n = 0; n < 4; n++) acc[i][n] = (f32x4){0.f, 0.f, 0.f, 0.f};

    for (int k0 = 0; k0 < DMODEL; k0 += 32) {
        __syncthreads();
        {
            const u16* apz = Ctx + (size_t)(m0 + ar) * DMODEL + k0 + ac;
            *(u16x8*)&Al[ar][ac] = *(const u16x8*)apz;
            *(u16x8*)&Al[ar][ac + 8] = *(const u16x8*)(apz + 8);
            const u16* wp = Wo + (size_t)(n0 + ar) * DMODEL + k0 + ac;
            *(u16x8*)&Bl[ar][ac] = *(const u16x8*)wp;
            *(u16x8*)&Bl[ar][ac + 8] = *(const u16x8*)(wp + 8);
        }
        __syncthreads();
        bf16x8 af[4], bfr[4];
#pragma unroll
        for (int i = 0; i < 4; i++) af[i] = ld_frag(&Al[wr + i * 16 + lr][lk]);
#pragma unroll
        for (int n = 0; n < 4; n++) bfr[n] = ld_frag(&Bl[wc + n * 16 + lr][lk]);
#pragma unroll
        for (int i = 0; i < 4; i++)
#pragma unroll
            for (int n = 0; n < 4; n++) acc[i][n] = MFMA16(af[i], bfr[n], acc[i][n]);
    }

    float bv[4];
#pragma unroll
    for (int n = 0; n < 4; n++) bv[n] = obias[n0 + wc + n * 16 + lr];
#pragma unroll
    for (int i = 0; i < 4; i++)
#pragma unroll
        for (int n = 0; n < 4; n++) {
            int ncol = n0 + wc + n * 16 + lr;
#pragma unroll
            for (int j = 0; j < 4; j++) {
                int m = m0 + wr + i * 16 + lkg * 4 + j;
                out[(size_t)m * DMODEL + ncol] = acc[i][n][j] + bv[n];
            }
        }
}

extern "C" void kernel_launch(void* const* d_in, const int* in_sizes, int n_in,
                              void* d_out, int out_size, void* d_ws, size_t ws_size,
                              hipStream_t stream) {
    const float* src   = (const float*)d_in[0];
    const float* w_in  = (const float*)d_in[1];
    const float* b_in  = (const float*)d_in[2];
    const float* w_out = (const float*)d_in[3];
    const float* b_out = (const float*)d_in[4];
    float* out = (float*)d_out;
    float* attnw = out + (size_t)S_LEN * BATCH * DMODEL;  // [B,S,S]

    // workspace layout
    float* Lr = (float*)d_ws;            // 131072 floats (1/l per bh,row)
    u16* Wqb = (u16*)(Lr + 131072);      // 786432
    u16* Wob = Wqb + 786432;             // 262144
    u16* Qs  = Wob + 262144;             // 8388608 each
    u16* Ks  = Qs + 8388608;
    u16* Vs  = Ks + 8388608;
    u16* Vt  = Vs + 8388608;
    u16* Ctx = Vt + 8388608;

    cast_weights<<<dim3(1024), dim3(256), 0, stream>>>(w_in, w_out, Wqb);
    qkv_gemm<<<dim3(12, 128), dim3(256), 0, stream>>>(src, Wqb, b_in, Qs, Ks, Vs);
    transpose_v<<<dim3(32, 64), dim3(256), 0, stream>>>(Vs, Vt);
    ctx_kernel<<<dim3(32, 64), dim3(256), 0, stream>>>(Qs, Ks, Vt, Lr, Ctx);
    mean_kernel<<<dim3(1024, 8), dim3(256), 0, stream>>>(Qs, Ks, Lr, attnw);
    out_gemm<<<dim3(4, 128), dim3(256), 0, stream>>>(Ctx, Wob, b_out, out);
}

// Round 3
// 457.813 us; speedup vs baseline: 2.0748x; 1.3494x over previous
//
#include <hip/hip_runtime.h>
#include <hip/hip_bf16.h>

#define S_LEN 2048
#define BATCH 8
#define DMODEL 512
#define NHEAD 8
#define HDIM 64

// Q pre-scale: (1/8) * log2(e) so softmax exponentials are raw v_exp_f32 (exp2)
#define QSCALE 0.18033688011112042f

typedef unsigned short u16;
typedef __bf16 bf16_t;
typedef bf16_t bf16x8 __attribute__((ext_vector_type(8)));
typedef float f32x4 __attribute__((ext_vector_type(4)));
typedef float f32x16 __attribute__((ext_vector_type(16)));
typedef u16 u16x8 __attribute__((ext_vector_type(8)));
typedef u16 u16x4 __attribute__((ext_vector_type(4)));
typedef unsigned u32x4 __attribute__((ext_vector_type(4)));

__device__ __forceinline__ u16 f2bf(float f) {
    unsigned u = __float_as_uint(f);
    u = (u + 0x7fffu + ((u >> 16) & 1u)) >> 16;
    return (u16)u;
}

__device__ __forceinline__ bf16x8 ld_frag(const u16* p) {
    u16x8 v = *(const u16x8*)p;
    return __builtin_bit_cast(bf16x8, v);
}

#define MFMA16(a, b, c) __builtin_amdgcn_mfma_f32_16x16x32_bf16((a), (b), (c), 0, 0, 0)
#define MFMA32(a, b, c) __builtin_amdgcn_mfma_f32_32x32x16_bf16((a), (b), (c), 0, 0, 0)
#define EXP2F(x) __builtin_amdgcn_exp2f(x)

__device__ __forceinline__ unsigned cvtpk(float lo, float hi) {
    unsigned r;
    asm("v_cvt_pk_bf16_f32 %0, %1, %2" : "=v"(r) : "v"(lo), "v"(hi));
    return r;
}
__device__ __forceinline__ void swap32(unsigned& a, unsigned& b) {
    asm("v_permlane32_swap_b32 %0, %1" : "+v"(a), "+v"(b));
}

// ---------------- cast weights fp32 -> bf16 ----------------
__global__ __launch_bounds__(256) void cast_weights(const float* __restrict__ wq,
                                                    const float* __restrict__ wo,
                                                    u16* __restrict__ dst) {
    int i = (blockIdx.x * 256 + threadIdx.x) * 4;  // 1048576 elems total
    float4 v;
    if (i < 786432) v = *(const float4*)(wq + i);
    else            v = *(const float4*)(wo + (i - 786432));
    u16x4 o = {f2bf(v.x), f2bf(v.y), f2bf(v.z), f2bf(v.w)};
    *(u16x4*)(dst + i) = o;
}

// ---------------- QKV projection GEMM ----------------
__global__ __launch_bounds__(256) void qkv_gemm(const float* __restrict__ src,
                                                const u16* __restrict__ Wq,
                                                const float* __restrict__ bias,
                                                u16* __restrict__ Qs,
                                                u16* __restrict__ Ks,
                                                u16* __restrict__ Vs) {
    __shared__ u16 Al[128][40];
    __shared__ u16 Bl[128][40];
    const int tid = threadIdx.x;
    const int lane = tid & 63, wid = tid >> 6;
    const int m0 = blockIdx.y * 128, n0 = blockIdx.x * 128;
    const int lr = lane & 15, lkg = lane >> 4, lk = lkg * 8;
    const int wr = (wid >> 1) * 64, wc = (wid & 1) * 64;
    const int ar = tid >> 1, ac = (tid & 1) * 16;

    f32x4 acc[4][4];
#pragma unroll
    for (int i = 0; i < 4; i++)
#pragma unroll
        for (int n = 0; n < 4; n++) acc[i][n] = (f32x4){0.f, 0.f, 0.f, 0.f};

    for (int k0 = 0; k0 < DMODEL; k0 += 32) {
        __syncthreads();
        {
            const float* sp = src + (size_t)(m0 + ar) * DMODEL + k0 + ac;
            float4 v0 = *(const float4*)(sp + 0);
            float4 v1 = *(const float4*)(sp + 4);
            float4 v2 = *(const float4*)(sp + 8);
            float4 v3 = *(const float4*)(sp + 12);
            u16x8 p0 = {f2bf(v0.x), f2bf(v0.y), f2bf(v0.z), f2bf(v0.w),
                        f2bf(v1.x), f2bf(v1.y), f2bf(v1.z), f2bf(v1.w)};
            u16x8 p1 = {f2bf(v2.x), f2bf(v2.y), f2bf(v2.z), f2bf(v2.w),
                        f2bf(v3.x), f2bf(v3.y), f2bf(v3.z), f2bf(v3.w)};
            *(u16x8*)&Al[ar][ac] = p0;
            *(u16x8*)&Al[ar][ac + 8] = p1;
            const u16* wp = Wq + (size_t)(n0 + ar) * DMODEL + k0 + ac;
            *(u16x8*)&Bl[ar][ac] = *(const u16x8*)wp;
            *(u16x8*)&Bl[ar][ac + 8] = *(const u16x8*)(wp + 8);
        }
        __syncthreads();
        bf16x8 af[4], bfr[4];
#pragma unroll
        for (int i = 0; i < 4; i++) af[i] = ld_frag(&Al[wr + i * 16 + lr][lk]);
#pragma unroll
        for (int n = 0; n < 4; n++) bfr[n] = ld_frag(&Bl[wc + n * 16 + lr][lk]);
#pragma unroll
        for (int i = 0; i < 4; i++)
#pragma unroll
            for (int n = 0; n < 4; n++) acc[i][n] = MFMA16(af[i], bfr[n], acc[i][n]);
    }

    float bv[4];
#pragma unroll
    for (int n = 0; n < 4; n++) bv[n] = bias[n0 + wc + n * 16 + lr];
#pragma unroll
    for (int i = 0; i < 4; i++) {
#pragma unroll
        for (int n = 0; n < 4; n++) {
            int ncol = n0 + wc + n * 16 + lr;
            int sect = ncol >> 9, idx = ncol & 511;
            int h = idx >> 6, d = idx & 63;
#pragma unroll
            for (int j = 0; j < 4; j++) {
                int m = m0 + wr + i * 16 + lkg * 4 + j;
                int srow = m >> 3, bidx = m & 7;
                float val = acc[i][n][j] + bv[n];
                size_t o = (((size_t)(bidx * NHEAD + h) * S_LEN) + srow) * HDIM + d;
                if (sect == 0)      Qs[o] = f2bf(val * QSCALE);
                else if (sect == 1) Ks[o] = f2bf(val);
                else                Vs[o] = f2bf(val);
            }
        }
    }
}

// ---------------- transpose V: [bh][s][64] -> [bh][64][s] ----------------
__global__ __launch_bounds__(256) void transpose_v(const u16* __restrict__ Vs,
                                                   u16* __restrict__ Vt) {
    __shared__ u16 tile[64][70];
    int bh = blockIdx.y, t0 = blockIdx.x * 64;
    int tid = threadIdx.x;
    int r = tid >> 2, c = (tid & 3) * 16;
    const u16* vp = Vs + ((size_t)bh * S_LEN + t0 + r) * HDIM + c;
    u16x8 x0 = *(const u16x8*)vp;
    u16x8 x1 = *(const u16x8*)(vp + 8);
#pragma unroll
    for (int i = 0; i < 8; i++) tile[r][c + i] = x0[i];
#pragma unroll
    for (int i = 0; i < 8; i++) tile[r][c + 8 + i] = x1[i];
    __syncthreads();
    int d0 = tid >> 2, tt = (tid & 3) * 16;
    u16x8 y0, y1;
#pragma unroll
    for (int i = 0; i < 8; i++) y0[i] = tile[tt + i][d0];
#pragma unroll
    for (int i = 0; i < 8; i++) y1[i] = tile[tt + 8 + i][d0];
    u16* op = Vt + ((size_t)bh * HDIM + d0) * S_LEN + t0 + tt;
    *(u16x8*)op = y0;
    *(u16x8*)(op + 8) = y1;
}

// ---------------- context: swapped-QK^T 32x32 flash attention ----------------
// 4 waves x 32 q-rows = 128 q-rows per block. K and Vt tiles (64 t) staged in
// XOR-swizzled LDS (write-side swizzle, reg-staged, issue-early/write-late),
// double-buffered, one barrier per tile. P stays in registers (swapped QK^T),
// repacked to PV A-frags via v_cvt_pk_bf16_f32 + v_permlane32_swap_b32.
__global__ __launch_bounds__(256) void ctx_kernel(const u16* __restrict__ Qs,
                                                  const u16* __restrict__ Ks,
                                                  const u16* __restrict__ Vt,
                                                  float* __restrict__ Lr,
                                                  u16* __restrict__ Ctx) {
    __shared__ char lds[32768];       // 2 bufs x (8K K + 8K V)
    __shared__ float cjl[4][32];
    const int tid = threadIdx.x, lane = tid & 63, wid = tid >> 6;
    const int l31 = lane & 31, hi = lane >> 5;
    const int bh = blockIdx.y, b = bh >> 3, h = bh & 7;
    const int q0w = blockIdx.x * 128 + wid * 32;
    const u16* Qb = Qs + (size_t)bh * S_LEN * HDIM;
    const u16* Kb = Ks + (size_t)bh * S_LEN * HDIM;
    const u16* Vb = Vt + (size_t)bh * HDIM * S_LEN;

    // Q B-fragments (held in registers for the whole block)
    bf16x8 qf[4];
#pragma unroll
    for (int kc = 0; kc < 4; kc++)
        qf[kc] = ld_frag(Qb + (size_t)(q0w + l31) * HDIM + kc * 16 + hi * 8);

    // staging geometry: thread covers 32B (two 16B chunks) of each 8KB tile
    const int o0 = tid * 32;
    const int srow = o0 >> 7, scol = o0 & 127;  // logical row / byte-col
    const int p0 = srow * 128 + (scol ^ ((srow & 7) << 4));
    const int p1 = srow * 128 + ((scol + 16) ^ ((srow & 7) << 4));
    const char* Ksrc = (const char*)Kb + (size_t)srow * 128 + scol;
    const char* Vsrc = (const char*)(Vb + (size_t)srow * S_LEN) + scol;

    u16x8 sreg0, sreg1, sreg2, sreg3;
    // prologue: stage tile 0
    sreg0 = *(const u16x8*)(Ksrc);
    sreg1 = *(const u16x8*)(Ksrc + 16);
    sreg2 = *(const u16x8*)(Vsrc);
    sreg3 = *(const u16x8*)(Vsrc + 16);
    *(u16x8*)(lds + p0) = sreg0;
    *(u16x8*)(lds + p1) = sreg1;
    *(u16x8*)(lds + 8192 + p0) = sreg2;
    *(u16x8*)(lds + 8192 + p1) = sreg3;
    __syncthreads();

    f32x16 cacc0, cacc1;
#pragma unroll
    for (int r = 0; r < 16; r++) { cacc0[r] = 0.f; cacc1[r] = 0.f; }
    float lsum = 0.f;
    int buf = 0;

    for (int it = 0; it < 32; ++it) {
        // issue next tile's global loads early (T14)
        if (it < 31) {
            const char* kn = Ksrc + (size_t)(it + 1) * 8192;      // K tile contiguous
            const char* vn = Vsrc + (size_t)(it + 1) * 128;       // Vt: +64 t cols
            sreg0 = *(const u16x8*)(kn);
            sreg1 = *(const u16x8*)(kn + 16);
            sreg2 = *(const u16x8*)(vn);
            sreg3 = *(const u16x8*)(vn + 16);
        }
        const char* Kl = lds + buf * 16384;
        const char* Vl = Kl + 8192;

        // QK^T (swapped): st[tt] = K_tile(tt) . Q  -> P^T[t][q=l31]
        f32x16 st0, st1;
#pragma unroll
        for (int r = 0; r < 16; r++) { st0[r] = 0.f; st1[r] = 0.f; }
        __builtin_amdgcn_s_setprio(1);
#pragma unroll
        for (int kc = 0; kc < 4; kc++) {
            int row0 = l31, row1 = 32 + l31;
            int c = kc * 32 + hi * 16;
            bf16x8 a0 = *(const bf16x8*)(Kl + row0 * 128 + (c ^ ((row0 & 7) << 4)));
            bf16x8 a1 = *(const bf16x8*)(Kl + row1 * 128 + (c ^ ((row1 & 7) << 4)));
            st0 = MFMA32(a0, qf[kc], st0);
            st1 = MFMA32(a1, qf[kc], st1);
        }
        __builtin_amdgcn_s_setprio(0);

        // softmax: unnormalized exp2, accumulate row sums (q = l31 lane-local)
#pragma unroll
        for (int r = 0; r < 16; r++) {
            float e0 = EXP2F(st0[r]);
            float e1 = EXP2F(st1[r]);
            lsum += e0 + e1;
            st0[r] = e0;
            st1[r] = e1;
        }

        // repack P -> PV A-frags: 16 cvt_pk + 8 permlane32_swap
        bf16x8 pa[4];
#pragma unroll
        for (int half = 0; half < 2; half++) {
            int h8 = half * 8;
            unsigned a0 = cvtpk(st0[h8 + 0], st0[h8 + 1]);
            unsigned b0 = cvtpk(st0[h8 + 4], st0[h8 + 5]);
            swap32(a0, b0);
            unsigned a1 = cvtpk(st0[h8 + 2], st0[h8 + 3]);
            unsigned b1 = cvtpk(st0[h8 + 6], st0[h8 + 7]);
            swap32(a1, b1);
            u32x4 w = {a0, a1, b0, b1};
            pa[half] = __builtin_bit_cast(bf16x8, w);
        }
#pragma unroll
        for (int half = 0; half < 2; half++) {
            int h8 = half * 8;
            unsigned a0 = cvtpk(st1[h8 + 0], st1[h8 + 1]);
            unsigned b0 = cvtpk(st1[h8 + 4], st1[h8 + 5]);
            swap32(a0, b0);
            unsigned a1 = cvtpk(st1[h8 + 2], st1[h8 + 3]);
            unsigned b1 = cvtpk(st1[h8 + 6], st1[h8 + 7]);
            swap32(a1, b1);
            u32x4 w = {a0, a1, b0, b1};
            pa[2 + half] = __builtin_bit_cast(bf16x8, w);
        }

        // PV: cacc[dc] += pa[ks] . Vt_tile[dc]
        __builtin_amdgcn_s_setprio(1);
#pragma unroll
        for (int ks = 0; ks < 4; ks++) {
            int c = ks * 32 + hi * 16;
            int row0 = l31, row1 = 32 + l31;
            bf16x8 v0 = *(const bf16x8*)(Vl + row0 * 128 + (c ^ ((row0 & 7) << 4)));
            bf16x8 v1 = *(const bf16x8*)(Vl + row1 * 128 + (c ^ ((row1 & 7) << 4)));
            cacc0 = MFMA32(pa[ks], v0, cacc0);
            cacc1 = MFMA32(pa[ks], v1, cacc1);
        }
        __builtin_amdgcn_s_setprio(0);

        // write next tile into the other buffer (loads have been in flight)
        if (it < 31) {
            char* d = lds + (buf ^ 1) * 16384;
            *(u16x8*)(d + p0) = sreg0;
            *(u16x8*)(d + p1) = sreg1;
            *(u16x8*)(d + 8192 + p0) = sreg2;
            *(u16x8*)(d + 8192 + p1) = sreg3;
        }
        __syncthreads();
        buf ^= 1;
    }

    // row sums: partner lane (^32) holds the other 16 t's of each 32-block
    float tot = lsum + __shfl_xor(lsum, 32);
    float cj = 1.0f / tot;
    if (hi == 0) {
        Lr[(size_t)bh * S_LEN + q0w + l31] = cj;
        cjl[wid][l31] = cj;
    }
    // redistribute cj from q-in-lane to q-in-row layout (same wave, no barrier)
    float cjr[16];
#pragma unroll
    for (int r = 0; r < 16; r++)
        cjr[r] = cjl[wid][(r & 3) + 8 * (r >> 2) + 4 * hi];

#pragma unroll
    for (int r = 0; r < 16; r++) {
        int q = q0w + (r & 3) + 8 * (r >> 2) + 4 * hi;
        size_t base = ((size_t)q * BATCH + b) * DMODEL + h * 64;
        Ctx[base + l31] = f2bf(cacc0[r] * cjr[r]);
        Ctx[base + 32 + l31] = f2bf(cacc1[r] * cjr[r]);
    }
}

// ---------------- mean of attention over heads ----------------
__global__ __launch_bounds__(256) void mean_kernel(const u16* __restrict__ Qs,
                                                   const u16* __restrict__ Ks,
                                                   const float* __restrict__ Lr,
                                                   float* __restrict__ attnw) {
    __shared__ u16 Kl[64][72];
    int b = blockIdx.y;
    int r0 = (blockIdx.x & 31) * 64, t0 = (blockIdx.x >> 5) * 64;
    int tid = threadIdx.x, lane = tid & 63, wid = tid >> 6;
    int lr = lane & 15, lkg = lane >> 4, lk = lkg * 8;
    int kr = tid >> 2, kc = (tid & 3) * 16;

    float cjh[8][4];
#pragma unroll
    for (int h = 0; h < 8; h++)
#pragma unroll
        for (int j = 0; j < 4; j++)
            cjh[h][j] = 0.125f *
                Lr[(size_t)(b * 8 + h) * S_LEN + r0 + wid * 16 + lkg * 4 + j];

    f32x4 macc[4];
#pragma unroll
    for (int n = 0; n < 4; n++) macc[n] = (f32x4){0.f, 0.f, 0.f, 0.f};

#pragma unroll
    for (int h = 0; h < 8; h++) {
        int bh = b * 8 + h;
        const u16* Qb = Qs + (size_t)bh * S_LEN * HDIM;
        const u16* Kb = Ks + (size_t)bh * S_LEN * HDIM;
        __syncthreads();
        {
            const u16* kp = Kb + (size_t)(t0 + kr) * HDIM + kc;
            *(u16x8*)&Kl[kr][kc] = *(const u16x8*)kp;
            *(u16x8*)&Kl[kr][kc + 8] = *(const u16x8*)(kp + 8);
        }
        __syncthreads();
        bf16x8 a0 = ld_frag(Qb + (size_t)(r0 + wid * 16 + lr) * HDIM + lk);
        bf16x8 a1 = ld_frag(Qb + (size_t)(r0 + wid * 16 + lr) * HDIM + 32 + lk);
        f32x4 sc[4];
#pragma unroll
        for (int n = 0; n < 4; n++) sc[n] = (f32x4){0.f, 0.f, 0.f, 0.f};
#pragma unroll
        for (int n = 0; n < 4; n++) {
            bf16x8 b0 = ld_frag(&Kl[n * 16 + lr][lk]);
            bf16x8 b1 = ld_frag(&Kl[n * 16 + lr][32 + lk]);
            sc[n] = MFMA16(a0, b0, sc[n]);
            sc[n] = MFMA16(a1, b1, sc[n]);
        }
#pragma unroll
        for (int n = 0; n < 4; n++)
#pragma unroll
            for (int j = 0; j < 4; j++)
                macc[n][j] += EXP2F(sc[n][j]) * cjh[h][j];
    }

#pragma unroll
    for (int n = 0; n < 4; n++)
#pragma unroll
        for (int j = 0; j < 4; j++) {
            int row = r0 + wid * 16 + lkg * 4 + j;
            attnw[((size_t)b * S_LEN + row) * S_LEN + t0 + n * 16 + lr] = macc[n][j];
        }
}

// ---------------- output projection GEMM ----------------
__global__ __launch_bounds__(256) void out_gemm(const u16* __restrict__ Ctx,
                                                const u16* __restrict__ Wo,
                                                const float* __restrict__ obias,
                                                float* __restrict__ out) {
    __shared__ u16 Al[128][40];
    __shared__ u16 Bl[128][40];
    const int tid = threadIdx.x;
    const int lane = tid & 63, wid = tid >> 6;
    const int m0 = blockIdx.y * 128, n0 = blockIdx.x * 128;
    const int lr = lane & 15, lkg = lane >> 4, lk = lkg * 8;
    const int wr = (wid >> 1) * 64, wc = (wid & 1) * 64;
    const int ar = tid >> 1, ac = (tid & 1) * 16;

    f32x4 acc[4][4];
#pragma unroll
    for (int i = 0; i < 4; i++)
#pragma unroll
        for (int n = 0; n < 4; n++) acc[i][n] = (f32x4){0.f, 0.f, 0.f, 0.f};

    for (int k0 = 0; k0 < DMODEL; k0 += 32) {
        __syncthreads();
        {
            const u16* apz = Ctx + (size_t)(m0 + ar) * DMODEL + k0 + ac;
            *(u16x8*)&Al[ar][ac] = *(const u16x8*)apz;
            *(u16x8*)&Al[ar][ac + 8] = *(const u16x8*)(apz + 8);
            const u16* wp = Wo + (size_t)(n0 + ar) * DMODEL + k0 + ac;
            *(u16x8*)&Bl[ar][ac] = *(const u16x8*)wp;
            *(u16x8*)&Bl[ar][ac + 8] = *(const u16x8*)(wp + 8);
        }
        __syncthreads();
        bf16x8 af[4], bfr[4];
#pragma unroll
        for (int i = 0; i < 4; i++) af[i] = ld_frag(&Al[wr + i * 16 + lr][lk]);
#pragma unroll
        for (int n = 0; n < 4; n++) bfr[n] = ld_frag(&Bl[wc + n * 16 + lr][lk]);
#pragma unroll
        for (int i = 0; i < 4; i++)
#pragma unroll
            for (int n = 0; n < 4; n++) acc[i][n] = MFMA16(af[i], bfr[n], acc[i][n]);
    }

    float bv[4];
#pragma unroll
    for (int n = 0; n < 4; n++) bv[n] = obias[n0 + wc + n * 16 + lr];
#pragma unroll
    for (int i = 0; i < 4; i++)
#pragma unroll
        for (int n = 0; n < 4; n++) {
            int ncol = n0 + wc + n * 16 + lr;
#pragma unroll
            for (int j = 0; j < 4; j++) {
                int m = m0 + wr + i * 16 + lkg * 4 + j;
                out[(size_t)m * DMODEL + ncol] = acc[i][n][j] + bv[n];
            }
        }
}

extern "C" void kernel_launch(void* const* d_in, const int* in_sizes, int n_in,
                              void* d_out, int out_size, void* d_ws, size_t ws_size,
                              hipStream_t stream) {
    const float* src   = (const float*)d_in[0];
    const float* w_in  = (const float*)d_in[1];
    const float* b_in  = (const float*)d_in[2];
    const float* w_out = (const float*)d_in[3];
    const float* b_out = (const float*)d_in[4];
    float* out = (float*)d_out;
    float* attnw = out + (size_t)S_LEN * BATCH * DMODEL;  // [B,S,S]

    // workspace layout
    float* Lr = (float*)d_ws;            // 131072 floats (1/l per bh,row)
    u16* Wqb = (u16*)(Lr + 131072);      // 786432
    u16* Wob = Wqb + 786432;             // 262144
    u16* Qs  = Wob + 262144;             // 8388608 each
    u16* Ks  = Qs + 8388608;
    u16* Vs  = Ks + 8388608;
    u16* Vt  = Vs + 8388608;
    u16* Ctx = Vt + 8388608;

    cast_weights<<<dim3(1024), dim3(256), 0, stream>>>(w_in, w_out, Wqb);
    qkv_gemm<<<dim3(12, 128), dim3(256), 0, stream>>>(src, Wqb, b_in, Qs, Ks, Vs);
    transpose_v<<<dim3(32, 64), dim3(256), 0, stream>>>(Vs, Vt);
    ctx_kernel<<<dim3(16, 64), dim3(256), 0, stream>>>(Qs, Ks, Vt, Lr, Ctx);
    mean_kernel<<<dim3(1024, 8), dim3(256), 0, stream>>>(Qs, Ks, Lr, attnw);
    out_gemm<<<dim3(4, 128), dim3(256), 0, stream>>>(Ctx, Wob, b_out, out);
}